// Round 10
// baseline (2430.825 us; speedup 1.0000x reference)
//
#include <hip/hip_runtime.h>
#include <math.h>

#define DIN   192
#define HD    256
#define ROWS  32
#define THREADS 256
#define LSTR  256

typedef __bf16 bf16_t;
typedef bf16_t bf16x8 __attribute__((ext_vector_type(8)));
typedef unsigned short u16x8 __attribute__((ext_vector_type(8)));
typedef float  f32x16 __attribute__((ext_vector_type(16)));

static __device__ __forceinline__ f32x16 mfma32(bf16x8 a, bf16x8 b, f32x16 c) {
  return __builtin_amdgcn_mfma_f32_32x32x16_bf16(a, b, c, 0, 0, 0);
}
static __device__ __forceinline__ unsigned short f2bfu(float f) {
  bf16_t h = (bf16_t)f; unsigned short u; __builtin_memcpy(&u, &h, 2); return u;
}
static __device__ __forceinline__ float bfu2f(unsigned short u) {
  unsigned x = ((unsigned)u) << 16; float f; __builtin_memcpy(&f, &x, 4); return f;
}
static __device__ __forceinline__ unsigned pk2(float a, float b) {
  return (unsigned)f2bfu(a) | ((unsigned)f2bfu(b) << 16);
}
static __device__ __forceinline__ float lo16(unsigned u) { return bfu2f((unsigned short)(u & 0xffff)); }
static __device__ __forceinline__ float hi16(unsigned u) { return bfu2f((unsigned short)(u >> 16)); }
static __device__ __forceinline__ float sigm(float x) {
  return __builtin_amdgcn_rcpf(1.f + __expf(-x));
}
// XOR-swizzled LDS element index (b16 granularity)
static __device__ __forceinline__ int lidx(int row, int col) {
  return row * LSTR + (col ^ ((row & 7) << 3));
}
// C-layout row for 32x32 MFMA (m74/m101): row = (r&3) + 8*(r>>2) + 4*kg
static __device__ __forceinline__ int crow(int r, int kg) {
  return (r & 3) + 8 * (r >> 2) + 4 * kg;
}

// bf16 weight regions (elements) in d_ws after scores buffer.
// Fragment order: ((tile*KS + ks)*64 + lane)*8 + j; tile=ocol>>5,
// lane=kg*32+(ocol&31), k=ks*16+kg*8+j. out_w padded 4->32 cols.
#define OFF_WSW1 0
#define OFF_WSS1 49152
#define OFF_WSG1 98304
#define OFF_WSC1 147456
#define OFF_WSW2 212992
#define OFF_WSS2 278528
#define OFF_WSG2 344064
#define OFF_WSC2 409600
#define OFF_WOUT 475136
#define NGRP_REORD 59392
#define NGRP_ALL   60416

__global__ void iab_wconv_kernel(const float* __restrict__ a0, const float* __restrict__ a1,
                                 const float* __restrict__ a2, const float* __restrict__ a3,
                                 const float* __restrict__ a4, const float* __restrict__ a5,
                                 const float* __restrict__ a6, const float* __restrict__ a7,
                                 const float* __restrict__ a8, unsigned short* __restrict__ out)
{
  const int i = blockIdx.x * 256 + threadIdx.x;
  if (i >= NGRP_ALL) return;
  if (i >= NGRP_REORD) {                       // out_w padded fragment tile
    const int g  = i - NGRP_REORD;             // [0, 1024)
    const int ks = g >> 6;
    const int ln = g & 63;
    const int col = ln & 31;
    const int kg  = ln >> 5;
    #pragma unroll
    for (int j = 0; j < 8; ++j) {
      const float vv = (col < 4) ? a8[col * 256 + ks * 16 + kg * 8 + j] : 0.f;
      out[OFF_WOUT + (size_t)g * 8 + j] = f2bfu(vv);
    }
    return;
  }
  const float* src; int off, Kd, g;
  if      (i < 6144)  { src = a0; off = OFF_WSW1; Kd = 192; g = i; }
  else if (i < 12288) { src = a1; off = OFF_WSS1; Kd = 192; g = i - 6144; }
  else if (i < 18432) { src = a2; off = OFF_WSG1; Kd = 192; g = i - 12288; }
  else if (i < 26624) { src = a3; off = OFF_WSC1; Kd = 256; g = i - 18432; }
  else if (i < 34816) { src = a4; off = OFF_WSW2; Kd = 256; g = i - 26624; }
  else if (i < 43008) { src = a5; off = OFF_WSS2; Kd = 256; g = i - 34816; }
  else if (i < 51200) { src = a6; off = OFF_WSG2; Kd = 256; g = i - 43008; }
  else                { src = a7; off = OFF_WSC2; Kd = 256; g = i - 51200; }
  const int KS   = Kd >> 4;
  const int tile = g / (KS * 64);
  const int rem  = g - tile * (KS * 64);
  const int ks   = rem >> 6;
  const int ln   = rem & 63;
  const float* sp = src + (size_t)(tile * 32 + (ln & 31)) * Kd + ks * 16 + (ln >> 5) * 8;
  #pragma unroll
  for (int j = 0; j < 8; ++j) out[off + (size_t)g * 8 + j] = f2bfu(sp[j]);
}

// single-matrix GEMM pass, one 32-row m-tile
template<int KS>
static __device__ __forceinline__ void gemm1(const unsigned short* __restrict__ Wt,
                                             const unsigned short* __restrict__ sIn,
                                             int l31, int kg, int xr, f32x16& acc)
{
  #pragma unroll 4
  for (int ks = 0; ks < KS; ++ks) {
    const bf16x8 Wc = *(const bf16x8*)(Wt + ks * 512);
    const bf16x8 A  = *(const bf16x8*)(sIn + l31 * LSTR + (((ks * 16) + kg * 8) ^ xr));
    acc = mfma32(A, Wc, acc);
  }
}

// paired GEMM pass (shared A stream)
template<int KS>
static __device__ __forceinline__ void gemm1p(const unsigned short* __restrict__ Wa,
                                              const unsigned short* __restrict__ Wb,
                                              const unsigned short* __restrict__ sIn,
                                              int l31, int kg, int xr,
                                              f32x16& u, f32x16& s)
{
  #pragma unroll 4
  for (int ks = 0; ks < KS; ++ks) {
    const bf16x8 wa = *(const bf16x8*)(Wa + ks * 512);
    const bf16x8 wb = *(const bf16x8*)(Wb + ks * 512);
    const bf16x8 A  = *(const bf16x8*)(sIn + l31 * LSTR + (((ks * 16) + kg * 8) ^ xr));
    u = mfma32(A, wa, u);
    s = mfma32(A, wb, s);
  }
}

// b = silu(u) * s -> bf16 LDS (one m-tile)
static __device__ __forceinline__ void storeSilu1(unsigned short* dst, const f32x16 u,
                                                  const f32x16 s, int kg, int ocol)
{
  #pragma unroll
  for (int i = 0; i < 16; ++i) {
    const float x = u[i];
    dst[lidx(crow(i, kg), ocol)] = f2bfu(x * sigm(x) * s[i]);
  }
}

// write 8 packed words (one m-tile) to LDS
static __device__ __forceinline__ void storePk1(unsigned short* dst, const unsigned* xp,
                                                int kg, int ocol)
{
  #pragma unroll
  for (int p = 0; p < 8; ++p) {
    const int row0 = crow(2 * p, kg);
    const unsigned pk = xp[p];
    dst[lidx(row0,     ocol)] = (unsigned short)(pk & 0xffff);
    dst[lidx(row0 + 1, ocol)] = (unsigned short)(pk >> 16);
  }
}

// one col-tile of a swiglu "b" phase: b = silu(x@Wa)*(x@Wb) -> sOut
template<int KS>
static __device__ __forceinline__ void bphase(const unsigned short* __restrict__ Wa,
                                              const unsigned short* __restrict__ Wb,
                                              const unsigned short* __restrict__ sIn,
                                              unsigned short* sOut,
                                              int l31, int kg, int xr, int ocol)
{
  f32x16 u{}, s{};
  gemm1p<KS>(Wa, Wb, sIn, l31, kg, xr, u, s);
  storeSilu1(sOut, u, s, kg, ocol);
}

// one col-tile of the gate*scale phase:
// RES=0: xp = sig(xA@Wg + bias) * (xB@Wc)      (x2, TB1)
// RES=1: xp += sig(...) * (...)                (xf = x2 + y, TB2)
template<int KSG, int KSC, int RES>
static __device__ __forceinline__ void cphase(const unsigned short* __restrict__ Wg,
                                              const unsigned short* __restrict__ Wc_,
                                              const unsigned short* __restrict__ sAin,
                                              const unsigned short* __restrict__ sBin,
                                              int l31, int kg, int xr, float bias,
                                              unsigned (&xp)[8])
{
  f32x16 g{};
  gemm1<KSG>(Wg, sAin, l31, kg, xr, g);
  f32x16 c{};
  gemm1<KSC>(Wc_, sBin, l31, kg, xr, c);
  #pragma unroll
  for (int p = 0; p < 8; ++p) {
    const float y0 = sigm(g[2*p]   + bias) * c[2*p];
    const float y1 = sigm(g[2*p+1] + bias) * c[2*p+1];
    if (RES) xp[p] = pk2(lo16(xp[p]) + y0, hi16(xp[p]) + y1);
    else     xp[p] = pk2(y0, y1);
  }
}

// ---------------------------------------------------------------------------
// Main fused kernel. 32 rows/block, 256 threads (4 waves), 32 KB LDS.
// __launch_bounds__(256,3): 3 waves/EU -> 3 blocks/CU (12 waves), reg cap
// ~170 total (arch+acc on gfx950 unified file). (256,4) caps total at 128
// -> 64 arch + 64 acc -> structural spills (R8/R9). 3 waves is the feasible
// middle between R6 (2 blocks, no spill) and R8 (4 blocks, spills).
// ---------------------------------------------------------------------------
__global__ __launch_bounds__(THREADS, 3)
void iab_rows_mfma(
    const float* __restrict__ v, const float* __restrict__ af,
    const float* __restrict__ fw, const float* __restrict__ fb,
    const float* __restrict__ ln1g, const float* __restrict__ ln1b,
    const float* __restrict__ bsig1,
    const float* __restrict__ ln2g, const float* __restrict__ ln2b,
    const float* __restrict__ bsig2,
    const float* __restrict__ outb,
    const unsigned short* __restrict__ wc,
    float* __restrict__ scores, int N)
{
  __shared__ __align__(16) unsigned short sA[ROWS * LSTR];  // xhat1 -> x2 -> xhat2 -> xf
  __shared__ __align__(16) unsigned short sB[ROWS * LSTR];  // b1 -> b2

  const int t    = threadIdx.x;
  const int w    = t >> 6;
  const int lane = t & 63;
  const int l31  = lane & 31;
  const int kg   = lane >> 5;
  const int xr   = (lane & 7) << 3;
  const int row0 = blockIdx.x * ROWS;
  const int oc0  = w * 64 + l31;
  const int oc1  = oc0 + 32;
  const int T0   = w * 2;
  const int T1   = w * 2 + 1;
  const int lb   = lane * 8;

  // ---- P0: features + LN1, 8 threads per row ----
  {
    const int r   = t >> 3;          // 0..31
    const int sub = t & 7;
    const int g   = row0 + r;
    const int xrr = (r & 7) << 3;
    float vx = 0.f, vy = 0.f, vz = 0.f;
    if (g < N) {
      vx = v[3 * (size_t)g + 0];
      vy = v[3 * (size_t)g + 1];
      vz = v[3 * (size_t)g + 2];
    }
    const float nrm = sqrtf(vx * vx + vy * vy + vz * vz);
    float e[24];
    {
      const float4 fwa = *(const float4*)(fw + sub * 8);
      const float4 fwb = *(const float4*)(fw + sub * 8 + 4);
      const float4 fba = *(const float4*)(fb + sub * 8);
      const float4 fbb = *(const float4*)(fb + sub * 8 + 4);
      e[0] = __cosf(6.283185307179586f * (nrm * fwa.x + fba.x));
      e[1] = __cosf(6.283185307179586f * (nrm * fwa.y + fba.y));
      e[2] = __cosf(6.283185307179586f * (nrm * fwa.z + fba.z));
      e[3] = __cosf(6.283185307179586f * (nrm * fwa.w + fba.w));
      e[4] = __cosf(6.283185307179586f * (nrm * fwb.x + fbb.x));
      e[5] = __cosf(6.283185307179586f * (nrm * fwb.y + fbb.y));
      e[6] = __cosf(6.283185307179586f * (nrm * fwb.z + fbb.z));
      e[7] = __cosf(6.283185307179586f * (nrm * fwb.w + fbb.w));
    }
    if (g < N) {
      const float* ap = af + (size_t)g * 128 + sub * 8;
      const float4 a0 = *(const float4*)(ap);
      const float4 a1 = *(const float4*)(ap + 4);
      const float4 a2 = *(const float4*)(ap + 64);
      const float4 a3 = *(const float4*)(ap + 68);
      e[8]  = a0.x; e[9]  = a0.y; e[10] = a0.z; e[11] = a0.w;
      e[12] = a1.x; e[13] = a1.y; e[14] = a1.z; e[15] = a1.w;
      e[16] = a2.x; e[17] = a2.y; e[18] = a2.z; e[19] = a2.w;
      e[20] = a3.x; e[21] = a3.y; e[22] = a3.z; e[23] = a3.w;
    } else {
      #pragma unroll
      for (int j = 8; j < 24; ++j) e[j] = 0.f;
    }
    float s = 0.f, sq = 0.f;
    #pragma unroll
    for (int j = 0; j < 24; ++j) { s += e[j]; sq += e[j] * e[j]; }
    #pragma unroll
    for (int o = 1; o < 8; o <<= 1) {
      s  += __shfl_xor(s,  o);
      sq += __shfl_xor(sq, o);
    }
    const float mean = s * (1.f / 192.f);
    const float var  = fmaxf(sq * (1.f / 192.f) - mean * mean, 0.f);
    const float rstd = rsqrtf(var + 1e-5f);
    #pragma unroll
    for (int ch = 0; ch < 3; ++ch) {
      const int base = ch * 64 + sub * 8;
      const float4 ga = *(const float4*)(ln1g + base);
      const float4 gb = *(const float4*)(ln1g + base + 4);
      const float4 oa = *(const float4*)(ln1b + base);
      const float4 ob = *(const float4*)(ln1b + base + 4);
      u16x8 p;
      p[0] = f2bfu((e[ch*8+0] - mean) * rstd * ga.x + oa.x);
      p[1] = f2bfu((e[ch*8+1] - mean) * rstd * ga.y + oa.y);
      p[2] = f2bfu((e[ch*8+2] - mean) * rstd * ga.z + oa.z);
      p[3] = f2bfu((e[ch*8+3] - mean) * rstd * ga.w + oa.w);
      p[4] = f2bfu((e[ch*8+4] - mean) * rstd * gb.x + ob.x);
      p[5] = f2bfu((e[ch*8+5] - mean) * rstd * gb.y + ob.y);
      p[6] = f2bfu((e[ch*8+6] - mean) * rstd * gb.z + ob.z);
      p[7] = f2bfu((e[ch*8+7] - mean) * rstd * gb.w + ob.w);
      *(u16x8*)(sA + r * LSTR + (base ^ xrr)) = p;
    }
  }
  __syncthreads();

  unsigned x2a[8], x2b[8];   // packed x2 per col-tile (TB1 out -> TB2 residual)

  // ---- B1: b1 = silu(x@Wsw1)*(x@Wss1) -> sB, two sequential col-tiles ----
  bphase<12>(wc + OFF_WSW1 + T0 * 12 * 512 + lb,
             wc + OFF_WSS1 + T0 * 12 * 512 + lb, sA, sB, l31, kg, xr, oc0);
  __builtin_amdgcn_sched_barrier(0);
  bphase<12>(wc + OFF_WSW1 + T1 * 12 * 512 + lb,
             wc + OFF_WSS1 + T1 * 12 * 512 + lb, sA, sB, l31, kg, xr, oc1);
  __syncthreads();   // b1 visible; xhat1 in sA still intact

  // ---- C: x2 = sig(xhat1@Wsg1+b)*(b1@Wsc1) -> x2a/x2b (regs only) ----
  cphase<12, 16, 0>(wc + OFF_WSG1 + T0 * 12 * 512 + lb,
                    wc + OFF_WSC1 + T0 * 16 * 512 + lb,
                    sA, sB, l31, kg, xr, bsig1[oc0], x2a);
  __builtin_amdgcn_sched_barrier(0);
  cphase<12, 16, 0>(wc + OFF_WSG1 + T1 * 12 * 512 + lb,
                    wc + OFF_WSC1 + T1 * 16 * 512 + lb,
                    sA, sB, l31, kg, xr, bsig1[oc1], x2b);
  __syncthreads();   // all xhat1/b1 reads complete

  storePk1(sA, x2a, kg, oc0);
  storePk1(sA, x2b, kg, oc1);
  __syncthreads();

  // ---- LN2: 8 threads per row over sA ----
  {
    const int r   = t >> 3;
    const int sub = t & 7;
    const int xrr = (r & 7) << 3;
    u16x8 rv0 = *(const u16x8*)(sA + r * LSTR + ((sub * 32 +  0) ^ xrr));
    u16x8 rv1 = *(const u16x8*)(sA + r * LSTR + ((sub * 32 +  8) ^ xrr));
    u16x8 rv2 = *(const u16x8*)(sA + r * LSTR + ((sub * 32 + 16) ^ xrr));
    u16x8 rv3 = *(const u16x8*)(sA + r * LSTR + ((sub * 32 + 24) ^ xrr));
    float e[32];
    #pragma unroll
    for (int j = 0; j < 8; ++j) {
      e[j]      = bfu2f(rv0[j]);
      e[8 + j]  = bfu2f(rv1[j]);
      e[16 + j] = bfu2f(rv2[j]);
      e[24 + j] = bfu2f(rv3[j]);
    }
    float s = 0.f, sq = 0.f;
    #pragma unroll
    for (int j = 0; j < 32; ++j) { s += e[j]; sq += e[j] * e[j]; }
    #pragma unroll
    for (int o = 1; o < 8; o <<= 1) {
      s  += __shfl_xor(s,  o);
      sq += __shfl_xor(sq, o);
    }
    const float mean = s * (1.f / 256.f);
    const float var  = fmaxf(sq * (1.f / 256.f) - mean * mean, 0.f);
    const float rstd = rsqrtf(var + 1e-5f);
    #pragma unroll
    for (int c = 0; c < 4; ++c) {
      const int base = sub * 32 + c * 8;
      const float4 ga = *(const float4*)(ln2g + base);
      const float4 gb = *(const float4*)(ln2g + base + 4);
      const float4 oa = *(const float4*)(ln2b + base);
      const float4 ob = *(const float4*)(ln2b + base + 4);
      u16x8 p;
      p[0] = f2bfu((e[c*8+0] - mean) * rstd * ga.x + oa.x);
      p[1] = f2bfu((e[c*8+1] - mean) * rstd * ga.y + oa.y);
      p[2] = f2bfu((e[c*8+2] - mean) * rstd * ga.z + oa.z);
      p[3] = f2bfu((e[c*8+3] - mean) * rstd * ga.w + oa.w);
      p[4] = f2bfu((e[c*8+4] - mean) * rstd * gb.x + ob.x);
      p[5] = f2bfu((e[c*8+5] - mean) * rstd * gb.y + ob.y);
      p[6] = f2bfu((e[c*8+6] - mean) * rstd * gb.z + ob.z);
      p[7] = f2bfu((e[c*8+7] - mean) * rstd * gb.w + ob.w);
      *(u16x8*)(sA + r * LSTR + (base ^ xrr)) = p;
    }
  }
  __syncthreads();

  // ---- D1: b2 = silu(xhat2@Wsw2)*(xhat2@Wss2) -> sB ----
  bphase<16>(wc + OFF_WSW2 + T0 * 16 * 512 + lb,
             wc + OFF_WSS2 + T0 * 16 * 512 + lb, sA, sB, l31, kg, xr, oc0);
  __builtin_amdgcn_sched_barrier(0);
  bphase<16>(wc + OFF_WSW2 + T1 * 16 * 512 + lb,
             wc + OFF_WSS2 + T1 * 16 * 512 + lb, sA, sB, l31, kg, xr, oc1);
  __syncthreads();   // b2 visible; xhat2 in sA still intact

  // ---- D23: xf = x2 + sig(xhat2@Wsg2+b)*(b2@Wsc2) -> x2a/x2b ----
  cphase<16, 16, 1>(wc + OFF_WSG2 + T0 * 16 * 512 + lb,
                    wc + OFF_WSC2 + T0 * 16 * 512 + lb,
                    sA, sB, l31, kg, xr, bsig2[oc0], x2a);
  __builtin_amdgcn_sched_barrier(0);
  cphase<16, 16, 1>(wc + OFF_WSG2 + T1 * 16 * 512 + lb,
                    wc + OFF_WSC2 + T1 * 16 * 512 + lb,
                    sA, sB, l31, kg, xr, bsig2[oc1], x2b);
  __syncthreads();   // all xhat2/b2 reads complete

  storePk1(sA, x2a, kg, oc0);
  storePk1(sA, x2b, kg, oc1);
  __syncthreads();

  // ---- F: scores = xf @ out_w^T + out_b via MFMA (wave 0) ----
  if (w == 0) {
    const unsigned short* WtF = wc + OFF_WOUT + (size_t)lane * 8;
    f32x16 c{};
    #pragma unroll 4
    for (int ks = 0; ks < 16; ++ks) {
      const bf16x8 wf = *(const bf16x8*)(WtF + ks * 512);
      const bf16x8 A  = *(const bf16x8*)(sA + l31 * LSTR + (((ks * 16) + kg * 8) ^ xr));
      c = mfma32(A, wf, c);
    }
    if (l31 < 4) {
      const float bias = outb[l31];
      #pragma unroll
      for (int i = 0; i < 16; ++i) {
        const int g = row0 + crow(i, kg);
        if (g < N) scores[(size_t)g * 4 + l31] = c[i] + bias;
      }
    }
  }
}

// ---------------------------------------------------------------------------
// Segment softmax + weighted 3-vector pooling (sorted indices, wave/segment).
// ---------------------------------------------------------------------------
__device__ __forceinline__ int iab_lower_bound(const int* __restrict__ a, int n, int key)
{
  int lo = 0, hi = n;
  while (lo < hi) {
    const int mid = (lo + hi) >> 1;
    if (a[mid] < key) lo = mid + 1; else hi = mid;
  }
  return lo;
}

__global__ __launch_bounds__(256)
void iab_segpool_kernel(const float* __restrict__ scores,
                        const float* __restrict__ v,
                        const int* __restrict__ gidx,
                        float* __restrict__ out, int N, int E)
{
  const int seg  = blockIdx.x * 4 + (threadIdx.x >> 6);
  const int lane = threadIdx.x & 63;
  if (seg >= E) return;

  const int lo = iab_lower_bound(gidx, N, seg);
  const int hi = iab_lower_bound(gidx, N, seg + 1);

  const int h  = lane & 3;
  const int ro = lane >> 2;

  float m = -INFINITY;
  for (int base = lo; base < hi; base += 16) {
    const int r = base + ro;
    if (r < hi) m = fmaxf(m, scores[(size_t)r * 4 + h]);
  }
  #pragma unroll
  for (int o = 4; o < 64; o <<= 1) m = fmaxf(m, __shfl_xor(m, o));

  float ssum = 0.f, w0 = 0.f, w1 = 0.f, w2 = 0.f;
  for (int base = lo; base < hi; base += 16) {
    const int r = base + ro;
    if (r < hi) {
      const float e = expf(scores[(size_t)r * 4 + h] - m);
      ssum += e;
      w0 += e * v[3 * (size_t)r + 0];
      w1 += e * v[3 * (size_t)r + 1];
      w2 += e * v[3 * (size_t)r + 2];
    }
  }
  #pragma unroll
  for (int o = 4; o < 64; o <<= 1) {
    ssum += __shfl_xor(ssum, o);
    w0   += __shfl_xor(w0, o);
    w1   += __shfl_xor(w1, o);
    w2   += __shfl_xor(w2, o);
  }

  if (ro == 0) {
    const float inv = (hi > lo) ? (1.f / ssum) : 0.f;
    out[(size_t)seg * 12 + h * 3 + 0] = w0 * inv;
    out[(size_t)seg * 12 + h * 3 + 1] = w1 * inv;
    out[(size_t)seg * 12 + h * 3 + 2] = w2 * inv;
  }
}

// ---------------------------------------------------------------------------
extern "C" void kernel_launch(void* const* d_in, const int* in_sizes, int n_in,
                              void* d_out, int out_size, void* d_ws, size_t ws_size,
                              hipStream_t stream)
{
  const float* v     = (const float*)d_in[0];
  const float* af    = (const float*)d_in[1];
  const int*   gidx  = (const int*)  d_in[2];
  const float* fw    = (const float*)d_in[4];
  const float* fb    = (const float*)d_in[5];
  const float* ln1g  = (const float*)d_in[6];
  const float* ln1b  = (const float*)d_in[7];
  const float* wsw1  = (const float*)d_in[8];
  const float* wss1  = (const float*)d_in[9];
  const float* wsig1 = (const float*)d_in[10];
  const float* bsig1 = (const float*)d_in[11];
  const float* wsc1  = (const float*)d_in[12];
  const float* ln2g  = (const float*)d_in[13];
  const float* ln2b  = (const float*)d_in[14];
  const float* wsw2  = (const float*)d_in[15];
  const float* wss2  = (const float*)d_in[16];
  const float* wsig2 = (const float*)d_in[17];
  const float* bsig2 = (const float*)d_in[18];
  const float* wsc2  = (const float*)d_in[19];
  const float* outw  = (const float*)d_in[20];
  const float* outb  = (const float*)d_in[21];

  const int N = in_sizes[0] / 3;
  const int E = out_size / 12;

  float* scores = (float*)d_ws;                                   // N*4 f32 = 16 MB
  unsigned short* wcv = (unsigned short*)((char*)d_ws + (size_t)N * 4 * sizeof(float));

  hipLaunchKernelGGL(iab_wconv_kernel, dim3((NGRP_ALL + 255) / 256), dim3(256), 0, stream,
                     wsw1, wss1, wsig1, wsc1, wsw2, wss2, wsig2, wsc2, outw, wcv);

  hipLaunchKernelGGL(iab_rows_mfma, dim3((N + ROWS - 1) / ROWS), dim3(THREADS), 0, stream,
                     v, af, fw, fb, ln1g, ln1b, bsig1, ln2g, ln2b, bsig2, outb,
                     wcv, scores, N);

  hipLaunchKernelGGL(iab_segpool_kernel, dim3((E + 3) / 4), dim3(256), 0, stream,
                     scores, v, gidx, (float*)d_out, N, E);
}

// Round 11
// 2148.169 us; speedup vs baseline: 1.1316x; 1.1316x over previous
//
#include <hip/hip_runtime.h>
#include <math.h>

#define DIN   192
#define HD    256
#define ROWS  32
#define THREADS 256
#define LSTR  256

typedef __bf16 bf16_t;
typedef bf16_t bf16x8 __attribute__((ext_vector_type(8)));
typedef unsigned short u16x8 __attribute__((ext_vector_type(8)));
typedef float  f32x16 __attribute__((ext_vector_type(16)));

static __device__ __forceinline__ f32x16 mfma32(bf16x8 a, bf16x8 b, f32x16 c) {
  return __builtin_amdgcn_mfma_f32_32x32x16_bf16(a, b, c, 0, 0, 0);
}
static __device__ __forceinline__ unsigned short f2bfu(float f) {
  bf16_t h = (bf16_t)f; unsigned short u; __builtin_memcpy(&u, &h, 2); return u;
}
static __device__ __forceinline__ float bfu2f(unsigned short u) {
  unsigned x = ((unsigned)u) << 16; float f; __builtin_memcpy(&f, &x, 4); return f;
}
static __device__ __forceinline__ unsigned pk2(float a, float b) {
  return (unsigned)f2bfu(a) | ((unsigned)f2bfu(b) << 16);
}
static __device__ __forceinline__ float lo16(unsigned u) { return bfu2f((unsigned short)(u & 0xffff)); }
static __device__ __forceinline__ float hi16(unsigned u) { return bfu2f((unsigned short)(u >> 16)); }
static __device__ __forceinline__ float sigm(float x) {
  return __builtin_amdgcn_rcpf(1.f + __expf(-x));
}
// XOR-swizzled LDS element index (b16 granularity)
static __device__ __forceinline__ int lidx(int row, int col) {
  return row * LSTR + (col ^ ((row & 7) << 3));
}
// C-layout row for 32x32 MFMA (m74/m101): row = (r&3) + 8*(r>>2) + 4*kg
static __device__ __forceinline__ int crow(int r, int kg) {
  return (r & 3) + 8 * (r >> 2) + 4 * kg;
}

// bf16 weight regions (elements) in d_ws after scores buffer.
// Fragment order: ((tile*KS + ks)*64 + lane)*8 + j; tile=ocol>>5,
// lane=kg*32+(ocol&31), k=ks*16+kg*8+j. out_w padded 4->32 cols.
#define OFF_WSW1 0
#define OFF_WSS1 49152
#define OFF_WSG1 98304
#define OFF_WSC1 147456
#define OFF_WSW2 212992
#define OFF_WSS2 278528
#define OFF_WSG2 344064
#define OFF_WSC2 409600
#define OFF_WOUT 475136
#define NGRP_REORD 59392
#define NGRP_ALL   60416

__global__ void iab_wconv_kernel(const float* __restrict__ a0, const float* __restrict__ a1,
                                 const float* __restrict__ a2, const float* __restrict__ a3,
                                 const float* __restrict__ a4, const float* __restrict__ a5,
                                 const float* __restrict__ a6, const float* __restrict__ a7,
                                 const float* __restrict__ a8, unsigned short* __restrict__ out)
{
  const int i = blockIdx.x * 256 + threadIdx.x;
  if (i >= NGRP_ALL) return;
  if (i >= NGRP_REORD) {                       // out_w padded fragment tile
    const int g  = i - NGRP_REORD;             // [0, 1024)
    const int ks = g >> 6;
    const int ln = g & 63;
    const int col = ln & 31;
    const int kg  = ln >> 5;
    #pragma unroll
    for (int j = 0; j < 8; ++j) {
      const float vv = (col < 4) ? a8[col * 256 + ks * 16 + kg * 8 + j] : 0.f;
      out[OFF_WOUT + (size_t)g * 8 + j] = f2bfu(vv);
    }
    return;
  }
  const float* src; int off, Kd, g;
  if      (i < 6144)  { src = a0; off = OFF_WSW1; Kd = 192; g = i; }
  else if (i < 12288) { src = a1; off = OFF_WSS1; Kd = 192; g = i - 6144; }
  else if (i < 18432) { src = a2; off = OFF_WSG1; Kd = 192; g = i - 12288; }
  else if (i < 26624) { src = a3; off = OFF_WSC1; Kd = 256; g = i - 18432; }
  else if (i < 34816) { src = a4; off = OFF_WSW2; Kd = 256; g = i - 26624; }
  else if (i < 43008) { src = a5; off = OFF_WSS2; Kd = 256; g = i - 34816; }
  else if (i < 51200) { src = a6; off = OFF_WSG2; Kd = 256; g = i - 43008; }
  else                { src = a7; off = OFF_WSC2; Kd = 256; g = i - 51200; }
  const int KS   = Kd >> 4;
  const int tile = g / (KS * 64);
  const int rem  = g - tile * (KS * 64);
  const int ks   = rem >> 6;
  const int ln   = rem & 63;
  const float* sp = src + (size_t)(tile * 32 + (ln & 31)) * Kd + ks * 16 + (ln >> 5) * 8;
  #pragma unroll
  for (int j = 0; j < 8; ++j) out[off + (size_t)g * 8 + j] = f2bfu(sp[j]);
}

// single-matrix GEMM pass, one 32-row m-tile
template<int KS>
static __device__ __forceinline__ void gemm1(const unsigned short* __restrict__ Wt,
                                             const unsigned short* __restrict__ sIn,
                                             int l31, int kg, int xr, f32x16& acc)
{
  #pragma unroll 4
  for (int ks = 0; ks < KS; ++ks) {
    const bf16x8 Wc = *(const bf16x8*)(Wt + ks * 512);
    const bf16x8 A  = *(const bf16x8*)(sIn + l31 * LSTR + (((ks * 16) + kg * 8) ^ xr));
    acc = mfma32(A, Wc, acc);
  }
}

// paired GEMM pass (shared A stream)
template<int KS>
static __device__ __forceinline__ void gemm1p(const unsigned short* __restrict__ Wa,
                                              const unsigned short* __restrict__ Wb,
                                              const unsigned short* __restrict__ sIn,
                                              int l31, int kg, int xr,
                                              f32x16& u, f32x16& s)
{
  #pragma unroll 4
  for (int ks = 0; ks < KS; ++ks) {
    const bf16x8 wa = *(const bf16x8*)(Wa + ks * 512);
    const bf16x8 wb = *(const bf16x8*)(Wb + ks * 512);
    const bf16x8 A  = *(const bf16x8*)(sIn + l31 * LSTR + (((ks * 16) + kg * 8) ^ xr));
    u = mfma32(A, wa, u);
    s = mfma32(A, wb, s);
  }
}

// b = silu(u) * s -> bf16 LDS (one m-tile)
static __device__ __forceinline__ void storeSilu1(unsigned short* dst, const f32x16 u,
                                                  const f32x16 s, int kg, int ocol)
{
  #pragma unroll
  for (int i = 0; i < 16; ++i) {
    const float x = u[i];
    dst[lidx(crow(i, kg), ocol)] = f2bfu(x * sigm(x) * s[i]);
  }
}

// write 8 packed words (one m-tile) to LDS
static __device__ __forceinline__ void storePk1(unsigned short* dst, const unsigned* xp,
                                                int kg, int ocol)
{
  #pragma unroll
  for (int p = 0; p < 8; ++p) {
    const int row0 = crow(2 * p, kg);
    const unsigned pk = xp[p];
    dst[lidx(row0,     ocol)] = (unsigned short)(pk & 0xffff);
    dst[lidx(row0 + 1, ocol)] = (unsigned short)(pk >> 16);
  }
}

// one col-tile of a swiglu "b" phase: b = silu(x@Wa)*(x@Wb) -> sOut
template<int KS>
static __device__ __forceinline__ void bphase(const unsigned short* __restrict__ Wa,
                                              const unsigned short* __restrict__ Wb,
                                              const unsigned short* __restrict__ sIn,
                                              unsigned short* sOut,
                                              int l31, int kg, int xr, int ocol)
{
  f32x16 u{}, s{};
  gemm1p<KS>(Wa, Wb, sIn, l31, kg, xr, u, s);
  storeSilu1(sOut, u, s, kg, ocol);
}

// one col-tile of the gate*scale phase:
// RES=0: xp = sig(xA@Wg + bias) * (xB@Wc)      (x2, TB1)
// RES=1: xp += sig(...) * (...)                (xf = x2 + y, TB2)
template<int KSG, int KSC, int RES>
static __device__ __forceinline__ void cphase(const unsigned short* __restrict__ Wg,
                                              const unsigned short* __restrict__ Wc_,
                                              const unsigned short* __restrict__ sAin,
                                              const unsigned short* __restrict__ sBin,
                                              int l31, int kg, int xr, float bias,
                                              unsigned (&xp)[8])
{
  f32x16 g{};
  gemm1<KSG>(Wg, sAin, l31, kg, xr, g);
  f32x16 c{};
  gemm1<KSC>(Wc_, sBin, l31, kg, xr, c);
  #pragma unroll
  for (int p = 0; p < 8; ++p) {
    const float y0 = sigm(g[2*p]   + bias) * c[2*p];
    const float y1 = sigm(g[2*p+1] + bias) * c[2*p+1];
    if (RES) xp[p] = pk2(lo16(xp[p]) + y0, hi16(xp[p]) + y1);
    else     xp[p] = pk2(y0, y1);
  }
}

// accumulate sum / sum-of-squares over one packed chunk (8 bf16 values)
#define LNACC(P) { \
  float e_; \
  e_ = bfu2f(P[0]); s += e_; sq += e_ * e_; \
  e_ = bfu2f(P[1]); s += e_; sq += e_ * e_; \
  e_ = bfu2f(P[2]); s += e_; sq += e_ * e_; \
  e_ = bfu2f(P[3]); s += e_; sq += e_ * e_; \
  e_ = bfu2f(P[4]); s += e_; sq += e_ * e_; \
  e_ = bfu2f(P[5]); s += e_; sq += e_ * e_; \
  e_ = bfu2f(P[6]); s += e_; sq += e_ * e_; \
  e_ = bfu2f(P[7]); s += e_; sq += e_ * e_; }

// normalize one packed chunk with gamma/beta at GPTR/BPTR+base, store to sA
#define LNNORM(P, GPTR, BPTR, BASE) { \
  const int base_ = (BASE); \
  const float4 ga_ = *(const float4*)((GPTR) + base_); \
  const float4 gb_ = *(const float4*)((GPTR) + base_ + 4); \
  const float4 oa_ = *(const float4*)((BPTR) + base_); \
  const float4 ob_ = *(const float4*)((BPTR) + base_ + 4); \
  u16x8 q_; \
  q_[0] = f2bfu((bfu2f(P[0]) - mean) * rstd * ga_.x + oa_.x); \
  q_[1] = f2bfu((bfu2f(P[1]) - mean) * rstd * ga_.y + oa_.y); \
  q_[2] = f2bfu((bfu2f(P[2]) - mean) * rstd * ga_.z + oa_.z); \
  q_[3] = f2bfu((bfu2f(P[3]) - mean) * rstd * ga_.w + oa_.w); \
  q_[4] = f2bfu((bfu2f(P[4]) - mean) * rstd * gb_.x + ob_.x); \
  q_[5] = f2bfu((bfu2f(P[5]) - mean) * rstd * gb_.y + ob_.y); \
  q_[6] = f2bfu((bfu2f(P[6]) - mean) * rstd * gb_.z + ob_.z); \
  q_[7] = f2bfu((bfu2f(P[7]) - mean) * rstd * gb_.w + ob_.w); \
  *(u16x8*)(sA + r * LSTR + (base_ ^ xrr)) = q_; }

// ---------------------------------------------------------------------------
// Main fused kernel. 32 rows/block, 256 threads (4 waves), 32 KB LDS.
// __launch_bounds__(256,3): 3 blocks/CU (12 waves), ~168-reg unified budget.
// LayerNorms keep raw values PACKED (u16x8) and unpack 8-at-a-time for
// stats and normalize — no 24/32-float live arrays (R10's spill source).
// ---------------------------------------------------------------------------
__global__ __launch_bounds__(THREADS, 3)
void iab_rows_mfma(
    const float* __restrict__ v, const float* __restrict__ af,
    const float* __restrict__ fw, const float* __restrict__ fb,
    const float* __restrict__ ln1g, const float* __restrict__ ln1b,
    const float* __restrict__ bsig1,
    const float* __restrict__ ln2g, const float* __restrict__ ln2b,
    const float* __restrict__ bsig2,
    const float* __restrict__ outb,
    const unsigned short* __restrict__ wc,
    float* __restrict__ scores, int N)
{
  __shared__ __align__(16) unsigned short sA[ROWS * LSTR];  // xhat1 -> x2 -> xhat2 -> xf
  __shared__ __align__(16) unsigned short sB[ROWS * LSTR];  // b1 -> b2

  const int t    = threadIdx.x;
  const int w    = t >> 6;
  const int lane = t & 63;
  const int l31  = lane & 31;
  const int kg   = lane >> 5;
  const int xr   = (lane & 7) << 3;
  const int row0 = blockIdx.x * ROWS;
  const int oc0  = w * 64 + l31;
  const int oc1  = oc0 + 32;
  const int T0   = w * 2;
  const int T1   = w * 2 + 1;
  const int lb   = lane * 8;

  // ---- P0: features + LN1, 8 threads per row; packed-raw, chunked stats ----
  {
    const int r   = t >> 3;          // 0..31
    const int sub = t & 7;
    const int g   = row0 + r;
    const int xrr = (r & 7) << 3;
    float s = 0.f, sq = 0.f;
    u16x8 p0, p1 = {}, p2 = {};
    {
      float vx = 0.f, vy = 0.f, vz = 0.f;
      if (g < N) {
        vx = v[3 * (size_t)g + 0];
        vy = v[3 * (size_t)g + 1];
        vz = v[3 * (size_t)g + 2];
      }
      const float nrm = sqrtf(vx * vx + vy * vy + vz * vz);
      const float4 fwa = *(const float4*)(fw + sub * 8);
      const float4 fwb = *(const float4*)(fw + sub * 8 + 4);
      const float4 fba = *(const float4*)(fb + sub * 8);
      const float4 fbb = *(const float4*)(fb + sub * 8 + 4);
      const float e0 = __cosf(6.283185307179586f * (nrm * fwa.x + fba.x));
      const float e1 = __cosf(6.283185307179586f * (nrm * fwa.y + fba.y));
      const float e2 = __cosf(6.283185307179586f * (nrm * fwa.z + fba.z));
      const float e3 = __cosf(6.283185307179586f * (nrm * fwa.w + fba.w));
      const float e4 = __cosf(6.283185307179586f * (nrm * fwb.x + fbb.x));
      const float e5 = __cosf(6.283185307179586f * (nrm * fwb.y + fbb.y));
      const float e6 = __cosf(6.283185307179586f * (nrm * fwb.z + fbb.z));
      const float e7 = __cosf(6.283185307179586f * (nrm * fwb.w + fbb.w));
      s  += e0 + e1 + e2 + e3 + e4 + e5 + e6 + e7;
      sq += e0*e0 + e1*e1 + e2*e2 + e3*e3 + e4*e4 + e5*e5 + e6*e6 + e7*e7;
      p0[0] = f2bfu(e0); p0[1] = f2bfu(e1); p0[2] = f2bfu(e2); p0[3] = f2bfu(e3);
      p0[4] = f2bfu(e4); p0[5] = f2bfu(e5); p0[6] = f2bfu(e6); p0[7] = f2bfu(e7);
    }
    if (g < N) {
      const float* ap = af + (size_t)g * 128 + sub * 8;
      {
        const float4 a0 = *(const float4*)(ap);
        const float4 a1 = *(const float4*)(ap + 4);
        s  += a0.x + a0.y + a0.z + a0.w + a1.x + a1.y + a1.z + a1.w;
        sq += a0.x*a0.x + a0.y*a0.y + a0.z*a0.z + a0.w*a0.w
            + a1.x*a1.x + a1.y*a1.y + a1.z*a1.z + a1.w*a1.w;
        p1[0] = f2bfu(a0.x); p1[1] = f2bfu(a0.y); p1[2] = f2bfu(a0.z); p1[3] = f2bfu(a0.w);
        p1[4] = f2bfu(a1.x); p1[5] = f2bfu(a1.y); p1[6] = f2bfu(a1.z); p1[7] = f2bfu(a1.w);
      }
      {
        const float4 a2 = *(const float4*)(ap + 64);
        const float4 a3 = *(const float4*)(ap + 68);
        s  += a2.x + a2.y + a2.z + a2.w + a3.x + a3.y + a3.z + a3.w;
        sq += a2.x*a2.x + a2.y*a2.y + a2.z*a2.z + a2.w*a2.w
            + a3.x*a3.x + a3.y*a3.y + a3.z*a3.z + a3.w*a3.w;
        p2[0] = f2bfu(a2.x); p2[1] = f2bfu(a2.y); p2[2] = f2bfu(a2.z); p2[3] = f2bfu(a2.w);
        p2[4] = f2bfu(a3.x); p2[5] = f2bfu(a3.y); p2[6] = f2bfu(a3.z); p2[7] = f2bfu(a3.w);
      }
    }
    #pragma unroll
    for (int o = 1; o < 8; o <<= 1) {
      s  += __shfl_xor(s,  o);
      sq += __shfl_xor(sq, o);
    }
    const float mean = s * (1.f / 192.f);
    const float var  = fmaxf(sq * (1.f / 192.f) - mean * mean, 0.f);
    const float rstd = rsqrtf(var + 1e-5f);
    LNNORM(p0, ln1g, ln1b, sub * 8);
    LNNORM(p1, ln1g, ln1b, 64 + sub * 8);
    LNNORM(p2, ln1g, ln1b, 128 + sub * 8);
  }
  __syncthreads();

  unsigned x2a[8], x2b[8];   // packed x2 per col-tile (TB1 out -> TB2 residual)

  // ---- B1: b1 = silu(x@Wsw1)*(x@Wss1) -> sB, two sequential col-tiles ----
  bphase<12>(wc + OFF_WSW1 + T0 * 12 * 512 + lb,
             wc + OFF_WSS1 + T0 * 12 * 512 + lb, sA, sB, l31, kg, xr, oc0);
  __builtin_amdgcn_sched_barrier(0);
  bphase<12>(wc + OFF_WSW1 + T1 * 12 * 512 + lb,
             wc + OFF_WSS1 + T1 * 12 * 512 + lb, sA, sB, l31, kg, xr, oc1);
  __syncthreads();   // b1 visible; xhat1 in sA still intact

  // ---- C: x2 = sig(xhat1@Wsg1+b)*(b1@Wsc1) -> x2a/x2b (regs only) ----
  cphase<12, 16, 0>(wc + OFF_WSG1 + T0 * 12 * 512 + lb,
                    wc + OFF_WSC1 + T0 * 16 * 512 + lb,
                    sA, sB, l31, kg, xr, bsig1[oc0], x2a);
  __builtin_amdgcn_sched_barrier(0);
  cphase<12, 16, 0>(wc + OFF_WSG1 + T1 * 12 * 512 + lb,
                    wc + OFF_WSC1 + T1 * 16 * 512 + lb,
                    sA, sB, l31, kg, xr, bsig1[oc1], x2b);
  __syncthreads();   // all xhat1/b1 reads complete

  storePk1(sA, x2a, kg, oc0);
  storePk1(sA, x2b, kg, oc1);
  __syncthreads();

  // ---- LN2: 8 threads per row; chunked two-pass over packed rv regs ----
  {
    const int r   = t >> 3;
    const int sub = t & 7;
    const int xrr = (r & 7) << 3;
    const u16x8 rv0 = *(const u16x8*)(sA + r * LSTR + ((sub * 32 +  0) ^ xrr));
    const u16x8 rv1 = *(const u16x8*)(sA + r * LSTR + ((sub * 32 +  8) ^ xrr));
    const u16x8 rv2 = *(const u16x8*)(sA + r * LSTR + ((sub * 32 + 16) ^ xrr));
    const u16x8 rv3 = *(const u16x8*)(sA + r * LSTR + ((sub * 32 + 24) ^ xrr));
    float s = 0.f, sq = 0.f;
    LNACC(rv0);
    LNACC(rv1);
    LNACC(rv2);
    LNACC(rv3);
    #pragma unroll
    for (int o = 1; o < 8; o <<= 1) {
      s  += __shfl_xor(s,  o);
      sq += __shfl_xor(sq, o);
    }
    const float mean = s * (1.f / 256.f);
    const float var  = fmaxf(sq * (1.f / 256.f) - mean * mean, 0.f);
    const float rstd = rsqrtf(var + 1e-5f);
    LNNORM(rv0, ln2g, ln2b, sub * 32 +  0);
    LNNORM(rv1, ln2g, ln2b, sub * 32 +  8);
    LNNORM(rv2, ln2g, ln2b, sub * 32 + 16);
    LNNORM(rv3, ln2g, ln2b, sub * 32 + 24);
  }
  __syncthreads();

  // ---- D1: b2 = silu(xhat2@Wsw2)*(xhat2@Wss2) -> sB ----
  bphase<16>(wc + OFF_WSW2 + T0 * 16 * 512 + lb,
             wc + OFF_WSS2 + T0 * 16 * 512 + lb, sA, sB, l31, kg, xr, oc0);
  __builtin_amdgcn_sched_barrier(0);
  bphase<16>(wc + OFF_WSW2 + T1 * 16 * 512 + lb,
             wc + OFF_WSS2 + T1 * 16 * 512 + lb, sA, sB, l31, kg, xr, oc1);
  __syncthreads();   // b2 visible; xhat2 in sA still intact

  // ---- D23: xf = x2 + sig(xhat2@Wsg2+b)*(b2@Wsc2) -> x2a/x2b ----
  cphase<16, 16, 1>(wc + OFF_WSG2 + T0 * 16 * 512 + lb,
                    wc + OFF_WSC2 + T0 * 16 * 512 + lb,
                    sA, sB, l31, kg, xr, bsig2[oc0], x2a);
  __builtin_amdgcn_sched_barrier(0);
  cphase<16, 16, 1>(wc + OFF_WSG2 + T1 * 16 * 512 + lb,
                    wc + OFF_WSC2 + T1 * 16 * 512 + lb,
                    sA, sB, l31, kg, xr, bsig2[oc1], x2b);
  __syncthreads();   // all xhat2/b2 reads complete

  storePk1(sA, x2a, kg, oc0);
  storePk1(sA, x2b, kg, oc1);
  __syncthreads();

  // ---- F: scores = xf @ out_w^T + out_b via MFMA (wave 0) ----
  if (w == 0) {
    const unsigned short* WtF = wc + OFF_WOUT + (size_t)lane * 8;
    f32x16 c{};
    #pragma unroll 4
    for (int ks = 0; ks < 16; ++ks) {
      const bf16x8 wf = *(const bf16x8*)(WtF + ks * 512);
      const bf16x8 A  = *(const bf16x8*)(sA + l31 * LSTR + (((ks * 16) + kg * 8) ^ xr));
      c = mfma32(A, wf, c);
    }
    if (l31 < 4) {
      const float bias = outb[l31];
      #pragma unroll
      for (int i = 0; i < 16; ++i) {
        const int g = row0 + crow(i, kg);
        if (g < N) scores[(size_t)g * 4 + l31] = c[i] + bias;
      }
    }
  }
}

// ---------------------------------------------------------------------------
// Segment softmax + weighted 3-vector pooling (sorted indices, wave/segment).
// ---------------------------------------------------------------------------
__device__ __forceinline__ int iab_lower_bound(const int* __restrict__ a, int n, int key)
{
  int lo = 0, hi = n;
  while (lo < hi) {
    const int mid = (lo + hi) >> 1;
    if (a[mid] < key) lo = mid + 1; else hi = mid;
  }
  return lo;
}

__global__ __launch_bounds__(256)
void iab_segpool_kernel(const float* __restrict__ scores,
                        const float* __restrict__ v,
                        const int* __restrict__ gidx,
                        float* __restrict__ out, int N, int E)
{
  const int seg  = blockIdx.x * 4 + (threadIdx.x >> 6);
  const int lane = threadIdx.x & 63;
  if (seg >= E) return;

  const int lo = iab_lower_bound(gidx, N, seg);
  const int hi = iab_lower_bound(gidx, N, seg + 1);

  const int h  = lane & 3;
  const int ro = lane >> 2;

  float m = -INFINITY;
  for (int base = lo; base < hi; base += 16) {
    const int r = base + ro;
    if (r < hi) m = fmaxf(m, scores[(size_t)r * 4 + h]);
  }
  #pragma unroll
  for (int o = 4; o < 64; o <<= 1) m = fmaxf(m, __shfl_xor(m, o));

  float ssum = 0.f, w0 = 0.f, w1 = 0.f, w2 = 0.f;
  for (int base = lo; base < hi; base += 16) {
    const int r = base + ro;
    if (r < hi) {
      const float e = expf(scores[(size_t)r * 4 + h] - m);
      ssum += e;
      w0 += e * v[3 * (size_t)r + 0];
      w1 += e * v[3 * (size_t)r + 1];
      w2 += e * v[3 * (size_t)r + 2];
    }
  }
  #pragma unroll
  for (int o = 4; o < 64; o <<= 1) {
    ssum += __shfl_xor(ssum, o);
    w0   += __shfl_xor(w0, o);
    w1   += __shfl_xor(w1, o);
    w2   += __shfl_xor(w2, o);
  }

  if (ro == 0) {
    const float inv = (hi > lo) ? (1.f / ssum) : 0.f;
    out[(size_t)seg * 12 + h * 3 + 0] = w0 * inv;
    out[(size_t)seg * 12 + h * 3 + 1] = w1 * inv;
    out[(size_t)seg * 12 + h * 3 + 2] = w2 * inv;
  }
}

// ---------------------------------------------------------------------------
extern "C" void kernel_launch(void* const* d_in, const int* in_sizes, int n_in,
                              void* d_out, int out_size, void* d_ws, size_t ws_size,
                              hipStream_t stream)
{
  const float* v     = (const float*)d_in[0];
  const float* af    = (const float*)d_in[1];
  const int*   gidx  = (const int*)  d_in[2];
  const float* fw    = (const float*)d_in[4];
  const float* fb    = (const float*)d_in[5];
  const float* ln1g  = (const float*)d_in[6];
  const float* ln1b  = (const float*)d_in[7];
  const float* wsw1  = (const float*)d_in[8];
  const float* wss1  = (const float*)d_in[9];
  const float* wsig1 = (const float*)d_in[10];
  const float* bsig1 = (const float*)d_in[11];
  const float* wsc1  = (const float*)d_in[12];
  const float* ln2g  = (const float*)d_in[13];
  const float* ln2b  = (const float*)d_in[14];
  const float* wsw2  = (const float*)d_in[15];
  const float* wss2  = (const float*)d_in[16];
  const float* wsig2 = (const float*)d_in[17];
  const float* bsig2 = (const float*)d_in[18];
  const float* wsc2  = (const float*)d_in[19];
  const float* outw  = (const float*)d_in[20];
  const float* outb  = (const float*)d_in[21];

  const int N = in_sizes[0] / 3;
  const int E = out_size / 12;

  float* scores = (float*)d_ws;                                   // N*4 f32 = 16 MB
  unsigned short* wcv = (unsigned short*)((char*)d_ws + (size_t)N * 4 * sizeof(float));

  hipLaunchKernelGGL(iab_wconv_kernel, dim3((NGRP_ALL + 255) / 256), dim3(256), 0, stream,
                     wsw1, wss1, wsig1, wsc1, wsw2, wss2, wsig2, wsc2, outw, wcv);

  hipLaunchKernelGGL(iab_rows_mfma, dim3((N + ROWS - 1) / ROWS), dim3(THREADS), 0, stream,
                     v, af, fw, fb, ln1g, ln1b, bsig1, ln2g, ln2b, bsig2, outb,
                     wcv, scores, N);

  hipLaunchKernelGGL(iab_segpool_kernel, dim3((E + 3) / 4), dim3(256), 0, stream,
                     scores, v, gidx, (float*)d_out, N, E);
}